// Round 1
// baseline (219.835 us; speedup 1.0000x reference)
//
#include <hip/hip_runtime.h>

// BinaryAggregationLayer: batch=4096, in_width=8192, out_width=8191.
// dest[i] = min(i, 8190)  =>  out[b][j] = x[b][j] for j<8190,
//                             out[b][8190] = 0.5*(x[b][8190]+x[b][8191])
// then clip to +-10000. Pure memory-bound strided copy.
//
// Flat-index mapping: o = b*8191 + j  ->  input i = b*8192 + j = o + b.

#define OUTW   8191
#define INW    8192
#define BATCH  4096
#define CLAMPV 10000.0f

__global__ __launch_bounds__(256) void bagg_copy_kernel(
    const float* __restrict__ x, float* __restrict__ out, unsigned int total4) {
    unsigned int t = blockIdx.x * blockDim.x + threadIdx.x;
    if (t >= total4) return;

    unsigned int o0 = t * 4u;                 // first flat output index (max ~33.5M, fits u32)
    unsigned int b  = o0 / OUTW;              // magic-mul division by 8191
    unsigned int j  = o0 - b * OUTW;

    float r[4];
#pragma unroll
    for (int k = 0; k < 4; ++k) {
        // current element: row b, col j ; input flat = o0 + k + b
        unsigned int i = o0 + (unsigned int)k + b;
        float v = x[i];
        if (j == OUTW - 1) {                  // merged node: mean of last two inputs
            v = 0.5f * (v + x[i + 1]);
        }
        v = fminf(fmaxf(v, -CLAMPV), CLAMPV);
        r[k] = v;
        // advance (j,b) for next element
        ++j;
        if (j == OUTW) { j = 0; ++b; }
    }

    float4 vv;
    vv.x = r[0]; vv.y = r[1]; vv.z = r[2]; vv.w = r[3];
    reinterpret_cast<float4*>(out)[t] = vv;   // out base is 16B aligned; total %4 == 0
}

extern "C" void kernel_launch(void* const* d_in, const int* in_sizes, int n_in,
                              void* d_out, int out_size, void* d_ws, size_t ws_size,
                              hipStream_t stream) {
    const float* x = (const float*)d_in[0];
    float* out = (float*)d_out;

    const unsigned int total  = (unsigned int)BATCH * (unsigned int)OUTW; // 33,550,336
    const unsigned int total4 = total / 4u;                               // 8,387,584 (exact)
    const unsigned int block  = 256;
    const unsigned int grid   = (total4 + block - 1) / block;             // 32,764

    bagg_copy_kernel<<<grid, block, 0, stream>>>(x, out, total4);
}